// Round 6
// baseline (723.714 us; speedup 1.0000x reference)
//
#include <hip/hip_runtime.h>

// Problem constants (fixed by the reference setup)
constexpr int N_NODES = 50000;
constexpr int G = 5;
constexpr int E = 850000;            // E0 (800000) + N self-loops
constexpr int GN = G * N_NODES;      // 250000
constexpr int GE = G * E;            // 4,250,000
constexpr float SLOPE = 0.2f;

// Bucket sort parameters
constexpr int NPB = 1024;                        // nodes per bucket
constexpr int NBUK = (GN + NPB - 1) / NPB;       // 245
constexpr int EPB = 4096;                        // edges per block (256 thr x 16)
constexpr int NBLK_E = (GE + EPB - 1) / EPB;     // 1038

static __device__ __forceinline__ float lrelu(float e) {
    return e > 0.f ? e : SLOPE * e;
}
static __device__ __forceinline__ unsigned short f2h(float f) {
    union { _Float16 h; unsigned short u; } v;
    v.h = (_Float16)f;
    return v.u;
}
static __device__ __forceinline__ float h2f(unsigned short u) {
    union { unsigned short u; _Float16 h; } v;
    v.u = u;
    return (float)v.h;
}

// ---------------- pass A1: per-block bucket histogram -----------------------
__global__ __launch_bounds__(256) void k_hist(const int* __restrict__ ei,
                                              int* __restrict__ H) {
    __shared__ int hist[NBUK];
    const int t = threadIdx.x, bi = blockIdx.x;
    for (int j = t; j < NBUK; j += 256) hist[j] = 0;
    __syncthreads();
#pragma unroll
    for (int i = 0; i < 16; ++i) {
        int idx = bi * EPB + i * 256 + t;
        if (idx < GE) {
            int g = idx / E;
            int el = idx - g * E;
            int dst = ei[(size_t)g * 2 * E + E + el];
            atomicAdd(&hist[(g * N_NODES + dst) >> 10], 1);
        }
    }
    __syncthreads();
    for (int j = t; j < NBUK; j += 256) H[(size_t)bi * NBUK + j] = hist[j];
}

// ------- pass A2a: per bucket, exclusive scan of H over blocks; totals ------
__global__ __launch_bounds__(256) void k_scanH(int* __restrict__ H,
                                               int* __restrict__ T) {
    __shared__ int s[256];
    const int t = threadIdx.x, b = blockIdx.x;
    int run = 0;
    for (int c = 0; c < NBLK_E; c += 256) {
        int bi = c + t;
        int v = (bi < NBLK_E) ? H[(size_t)bi * NBUK + b] : 0;
        s[t] = v;
        for (int off = 1; off < 256; off <<= 1) {
            __syncthreads();
            int u = (t >= off) ? s[t - off] : 0;
            __syncthreads();
            s[t] += u;
        }
        __syncthreads();
        int excl = s[t] - v;
        if (bi < NBLK_E) H[(size_t)bi * NBUK + b] = run + excl;
        run += s[255];
        __syncthreads();
    }
    if (t == 0) T[b] = run;
}

// ------- pass A2b: exclusive scan of bucket totals -> bucket bases ----------
__global__ __launch_bounds__(256) void k_scanT(const int* __restrict__ T,
                                               int* __restrict__ base_g) {
    __shared__ int s[256];
    const int t = threadIdx.x;
    int v = (t < NBUK) ? T[t] : 0;
    s[t] = v;
    for (int off = 1; off < 256; off <<= 1) {
        __syncthreads();
        int u = (t >= off) ? s[t - off] : 0;
        __syncthreads();
        s[t] += u;
    }
    __syncthreads();
    if (t < NBUK) base_g[t] = s[t] - v;
    if (t == 0) base_g[NBUK] = s[255];
}

// ------- pass A3: scatter packed (dstLow10<<18 | src) into bucket groups ----
__global__ __launch_bounds__(256) void k_scatter(const int* __restrict__ ei,
                                                 const int* __restrict__ H,
                                                 const int* __restrict__ base_g,
                                                 int* __restrict__ tmp) {
    __shared__ int cnt[NBUK];
    __shared__ int off[NBUK];
    const int t = threadIdx.x, bi = blockIdx.x;
    for (int j = t; j < NBUK; j += 256) {
        cnt[j] = 0;
        off[j] = base_g[j] + H[(size_t)bi * NBUK + j];
    }
    __syncthreads();
#pragma unroll
    for (int i = 0; i < 16; ++i) {
        int idx = bi * EPB + i * 256 + t;
        if (idx < GE) {
            int g = idx / E;
            int el = idx - g * E;
            const int* eb = ei + (size_t)g * 2 * E;
            int src = eb[el];
            int dst = eb[E + el];
            int gdst = g * N_NODES + dst;
            int b = gdst >> 10;
            int rank = atomicAdd(&cnt[b], 1);
            tmp[off[b] + rank] = ((gdst & 1023) << 18) | (g * N_NODES + src);
        }
    }
}

// ------- pass B: per-bucket LDS counting sort -> rowptr/deg/csr -------------
__global__ __launch_bounds__(256) void k_build(const int* __restrict__ base_g,
                                               const int* __restrict__ tmp,
                                               int* __restrict__ rowptr,
                                               int* __restrict__ deg,
                                               int* __restrict__ csr) {
    __shared__ int degL[NPB];
    __shared__ int curL[NPB];
    __shared__ int s[256];
    const int t = threadIdx.x, b = blockIdx.x;
    const int n0 = b << 10;
    const int nn = min(NPB, GN - n0);
    const int s0 = base_g[b], s1 = base_g[b + 1];
#pragma unroll
    for (int i = 0; i < 4; ++i) degL[t * 4 + i] = 0;
    __syncthreads();
    for (int i = s0 + t; i < s1; i += 256)
        atomicAdd(&degL[tmp[i] >> 18], 1);
    __syncthreads();
    int j0 = t * 4;
    int d0 = degL[j0], d1 = degL[j0 + 1], d2 = degL[j0 + 2], d3 = degL[j0 + 3];
    int tsum = d0 + d1 + d2 + d3;
    s[t] = tsum;
    for (int off = 1; off < 256; off <<= 1) {
        __syncthreads();
        int u = (t >= off) ? s[t - off] : 0;
        __syncthreads();
        s[t] += u;
    }
    __syncthreads();
    int excl = s[t] - tsum;
    int p0 = excl, p1 = p0 + d0, p2 = p1 + d1, p3 = p2 + d2;
    curL[j0] = p0; curL[j0 + 1] = p1; curL[j0 + 2] = p2; curL[j0 + 3] = p3;
    if (j0     < nn) { rowptr[n0 + j0]     = s0 + p0; deg[n0 + j0]     = d0; }
    if (j0 + 1 < nn) { rowptr[n0 + j0 + 1] = s0 + p1; deg[n0 + j0 + 1] = d1; }
    if (j0 + 2 < nn) { rowptr[n0 + j0 + 2] = s0 + p2; deg[n0 + j0 + 2] = d2; }
    if (j0 + 3 < nn) { rowptr[n0 + j0 + 3] = s0 + p3; deg[n0 + j0 + 3] = d3; }
    __syncthreads();
    for (int i = s0 + t; i < s1; i += 256) {
        int e = tmp[i];
        int r = atomicAdd(&curL[e >> 18], 1);
        csr[s0 + r] = e & 0x3FFFF;
    }
}

// --- GEMM1 + fused logits: h1f[GN][64] fp16 (128B rows), l1[GN][8] fp16,
//     ad1[GN][8] fp32
__global__ __launch_bounds__(256) void k_gemm1(const float* __restrict__ x,
                                               const float* __restrict__ W1,
                                               const float* __restrict__ a_src,
                                               const float* __restrict__ a_dst,
                                               unsigned short* __restrict__ h1f,
                                               unsigned short* __restrict__ l1,
                                               float* __restrict__ ad1) {
    __shared__ float Bs[128][68];
    __shared__ float As[64][65];
    __shared__ float aS[64], aD[64];
    const int t = threadIdx.x;
    const int rowBase = blockIdx.x * 64;

    const float4* W14 = (const float4*)W1;
#pragma unroll
    for (int i = 0; i < 8; ++i) {
        int v = t + i * 256;
        int k = v >> 4;
        int c = (v & 15) << 2;
        float4 w = W14[v];
        Bs[k][c] = w.x; Bs[k][c + 1] = w.y; Bs[k][c + 2] = w.z; Bs[k][c + 3] = w.w;
    }
    if (t < 64) { aS[t] = a_src[t]; aD[t] = a_dst[t]; }

    const int tx = t & 15;
    const int ty = t >> 4;
    float acc[4][4] = {};
    const float4* x4 = (const float4*)x;

    for (int kc = 0; kc < 128; kc += 64) {
        __syncthreads();
#pragma unroll
        for (int i = 0; i < 4; ++i) {
            int v = t + i * 256;
            int r = v >> 4;
            int kq = v & 15;
            int row = rowBase + r;
            float4 a = make_float4(0.f, 0.f, 0.f, 0.f);
            if (row < GN) a = x4[row * 32 + (kc >> 2) + kq];
            int kk = kq << 2;
            As[kk][r] = a.x; As[kk + 1][r] = a.y; As[kk + 2][r] = a.z; As[kk + 3][r] = a.w;
        }
        __syncthreads();
#pragma unroll 8
        for (int k = 0; k < 64; ++k) {
            float a0 = As[k][ty * 4 + 0];
            float a1 = As[k][ty * 4 + 1];
            float a2 = As[k][ty * 4 + 2];
            float a3 = As[k][ty * 4 + 3];
            float4 b = *(const float4*)&Bs[kc + k][tx * 4];
            acc[0][0] += a0 * b.x; acc[0][1] += a0 * b.y; acc[0][2] += a0 * b.z; acc[0][3] += a0 * b.w;
            acc[1][0] += a1 * b.x; acc[1][1] += a1 * b.y; acc[1][2] += a1 * b.z; acc[1][3] += a1 * b.w;
            acc[2][0] += a2 * b.x; acc[2][1] += a2 * b.y; acc[2][2] += a2 * b.z; acc[2][3] += a2 * b.w;
            acc[3][0] += a3 * b.x; acc[3][1] += a3 * b.y; acc[3][2] += a3 * b.z; acc[3][3] += a3 * b.w;
        }
    }
    const int head = tx >> 1;
    const int coff = (tx & 1) * 4;
#pragma unroll
    for (int i = 0; i < 4; ++i) {
        int row = rowBase + ty * 4 + i;
        float as_p = acc[i][0] * aS[head * 8 + coff]     + acc[i][1] * aS[head * 8 + coff + 1]
                   + acc[i][2] * aS[head * 8 + coff + 2] + acc[i][3] * aS[head * 8 + coff + 3];
        float ad_p = acc[i][0] * aD[head * 8 + coff]     + acc[i][1] * aD[head * 8 + coff + 1]
                   + acc[i][2] * aD[head * 8 + coff + 2] + acc[i][3] * aD[head * 8 + coff + 3];
        as_p += __shfl_xor(as_p, 1);
        ad_p += __shfl_xor(ad_p, 1);
        if (row < GN) {
            ushort4 fv = make_ushort4(f2h(acc[i][0]), f2h(acc[i][1]), f2h(acc[i][2]), f2h(acc[i][3]));
            *(ushort4*)(h1f + (size_t)row * 64 + tx * 4) = fv;
            if ((tx & 1) == 0) {
                l1[(size_t)row * 8 + head] = f2h(as_p);
                ad1[row * 8 + head] = ad_p;
            }
        }
    }
}

// ------- layer-1 gather: one wave/dst; reg-cached adjacency, 2-phase --------
__global__ __launch_bounds__(256) void k_layer1(const int* __restrict__ rowptr,
                                                const int* __restrict__ deg,
                                                const int* __restrict__ csr,
                                                const unsigned short* __restrict__ h1f,
                                                const unsigned short* __restrict__ l1,
                                                const float* __restrict__ ad1,
                                                unsigned short* __restrict__ out1h) {
    int d = __builtin_amdgcn_readfirstlane(blockIdx.x * 4 + (threadIdx.x >> 6));
    int tt = threadIdx.x & 63;          // h*8+c
    int h = tt >> 3;
    int start = rowptr[d];              // s_load
    int dg = deg[d];                    // s_load
    // phase-1 pairing: lane p handles (e = p>>3, h' = p&7)
    float adP = ad1[d * 8 + (tt & 7)];
    int sv = csr[start + min(tt, dg - 1)];   // whole adjacency in registers
    int full = min(dg, 64);
    float den = 0.f, acc = 0.f;
    for (int q = 0; q < full; q += 8) {
        // phase 1: 64 lanes = 8 edges x 8 heads -> one exp per (edge,head)
        int eAbs = q + (tt >> 3);
        int sE = __shfl(sv, eAbs & 63);
        float lg = h2f(l1[(size_t)sE * 8 + (tt & 7)]);
        float w = (eAbs < full) ? __expf(lrelu(lg + adP)) : 0.f;
        // phase 2: broadcast w, 8 independent feature gathers
#pragma unroll
        for (int e = 0; e < 8; ++e) {
            if (q + e >= full) break;   // wave-uniform exit
            float we = __shfl(w, (e << 3) | h);
            int s = __shfl(sv, q + e);
            den += we;
            acc += we * h2f(h1f[(size_t)s * 64 + tt]);
        }
    }
    // tail for deg > 64 (essentially never; correctness safety)
    if (dg > 64) {
        float adH = __shfl(adP, h);
        for (int j = 64; j < dg; ++j) {
            int s0 = csr[start + j];
            float w0 = __expf(lrelu(h2f(l1[(size_t)s0 * 8 + h]) + adH));
            den += w0;
            acc += w0 * h2f(h1f[(size_t)s0 * 64 + tt]);
        }
    }
    out1h[(size_t)d * 64 + tt] = f2h(acc / (den + 1e-16f));
}

// --- GEMM2 + fused logits: h2r[GN][20] fp16 (16 ch + logit in one 40B row) --
__global__ __launch_bounds__(256) void k_gemm2(const unsigned short* __restrict__ agg1,
                                               const float* __restrict__ b1,
                                               const float* __restrict__ W2,
                                               const float* __restrict__ a_src,
                                               const float* __restrict__ a_dst,
                                               unsigned short* __restrict__ h2r,
                                               float* __restrict__ ad2) {
    __shared__ float As[64][65];
    __shared__ float Bs[64][20];
    __shared__ float aS[16], aD[16];
    const int t = threadIdx.x;
    const int rowBase = blockIdx.x * 64;

    {
        int k = t >> 2, c = (t & 3) << 2;
        float4 w = ((const float4*)W2)[t];
        Bs[k][c] = w.x; Bs[k][c + 1] = w.y; Bs[k][c + 2] = w.z; Bs[k][c + 3] = w.w;
    }
    if (t < 16) { aS[t] = a_src[t]; aD[t] = a_dst[t]; }
    const ushort4* a4p = (const ushort4*)agg1;
    const float4* b14 = (const float4*)b1;
#pragma unroll
    for (int i = 0; i < 4; ++i) {
        int v = t + i * 256;
        int r = v >> 4;
        int kq = v & 15;
        int row = rowBase + r;
        float ax = 0.f, ay = 0.f, az = 0.f, aw = 0.f;
        if (row < GN) {
            ushort4 a = a4p[row * 16 + kq];
            float4 bb = b14[kq];
            ax = fmaxf(h2f(a.x) + bb.x, 0.f);
            ay = fmaxf(h2f(a.y) + bb.y, 0.f);
            az = fmaxf(h2f(a.z) + bb.z, 0.f);
            aw = fmaxf(h2f(a.w) + bb.w, 0.f);
        }
        int kk = kq << 2;
        As[kk][r] = ax; As[kk + 1][r] = ay; As[kk + 2][r] = az; As[kk + 3][r] = aw;
    }
    __syncthreads();
    const int r = t >> 2;
    const int cg = (t & 3) << 2;
    float acc0 = 0.f, acc1 = 0.f, acc2 = 0.f, acc3 = 0.f;
#pragma unroll 8
    for (int k = 0; k < 64; ++k) {
        float a = As[k][r];
        float4 b = *(const float4*)&Bs[k][cg];
        acc0 += a * b.x; acc1 += a * b.y; acc2 += a * b.z; acc3 += a * b.w;
    }
    float as_p = acc0 * aS[cg] + acc1 * aS[cg + 1] + acc2 * aS[cg + 2] + acc3 * aS[cg + 3];
    float ad_p = acc0 * aD[cg] + acc1 * aD[cg + 1] + acc2 * aD[cg + 2] + acc3 * aD[cg + 3];
    as_p += __shfl_xor(as_p, 1); as_p += __shfl_xor(as_p, 2);
    ad_p += __shfl_xor(ad_p, 1); ad_p += __shfl_xor(ad_p, 2);
    int row = rowBase + r;
    if (row < GN) {
        ushort4 fv = make_ushort4(f2h(acc0), f2h(acc1), f2h(acc2), f2h(acc3));
        *(ushort4*)(h2r + (size_t)row * 20 + cg) = fv;   // row*40B + cg*2 is 8B-aligned
        if ((t & 3) == 0) {
            h2r[(size_t)row * 20 + 16] = f2h(as_p);
            ad2[row] = ad_p;
        }
    }
}

// ------- layer-2 gather: one wave/dst, 16 ch x 4 edge-slots, reg adjacency --
__global__ __launch_bounds__(256) void k_layer2(const int* __restrict__ rowptr,
                                                const int* __restrict__ deg,
                                                const int* __restrict__ csr,
                                                const unsigned short* __restrict__ h2r,
                                                const float* __restrict__ ad2,
                                                float* __restrict__ out2) {
    int d = __builtin_amdgcn_readfirstlane(blockIdx.x * 4 + (threadIdx.x >> 6));
    int tt = threadIdx.x & 63;
    int c = tt & 15;
    int sub = tt >> 4;
    int start = rowptr[d];
    int dg = deg[d];
    float ad = ad2[d];
    int sv = csr[start + min(tt, dg - 1)];   // whole adjacency in registers
    int full = min(dg, 64);
    float den = 0.f, acc = 0.f;
    for (int base = 0; base < full; base += 4) {
        int j = base + sub;
        bool val = j < full;
        int s = __shfl(sv, j < 64 ? j : 0);
        const unsigned short* r = h2r + (size_t)s * 20;
        float w = val ? __expf(lrelu(h2f(r[16]) + ad)) : 0.f;
        float g = h2f(r[c]);
        den += w;
        acc += w * g;
    }
    // tail for deg > 64 (essentially never)
    for (int base = 64; base < dg; base += 4) {
        int j = base + sub;
        bool val = j < dg;
        int s = csr[start + (val ? j : 0)];
        const unsigned short* r = h2r + (size_t)s * 20;
        float w = val ? __expf(lrelu(h2f(r[16]) + ad)) : 0.f;
        float g = h2f(r[c]);
        den += w;
        acc += w * g;
    }
    acc += __shfl_xor(acc, 16); acc += __shfl_xor(acc, 32);
    den += __shfl_xor(den, 16); den += __shfl_xor(den, 32);
    if (sub == 0) out2[(size_t)d * 16 + c] = acc / (den + 1e-16f);
}

// -------- final: out[n,2] = concat_g(out2[g,n,:]+b2) @ Wf + bf --------------
__global__ __launch_bounds__(256) void k_final(const float* __restrict__ agg2,
                                               const float* __restrict__ b2,
                                               const float* __restrict__ Wf,
                                               const float* __restrict__ bf,
                                               float* __restrict__ out) {
    int n = blockIdx.x * 256 + threadIdx.x;
    if (n >= N_NODES) return;
    float o0 = bf[0], o1 = bf[1];
#pragma unroll
    for (int g = 0; g < G; ++g) {
        const float4* v4 = (const float4*)agg2 + (size_t)(g * N_NODES + n) * 4;
#pragma unroll
        for (int q = 0; q < 4; ++q) {
            float4 v = v4[q];
            float4 b = ((const float4*)b2)[q];
            v.x += b.x; v.y += b.y; v.z += b.z; v.w += b.w;
            int kb = g * 16 + q * 4;
            o0 += v.x * Wf[(kb + 0) * 2]     + v.y * Wf[(kb + 1) * 2]
                + v.z * Wf[(kb + 2) * 2]     + v.w * Wf[(kb + 3) * 2];
            o1 += v.x * Wf[(kb + 0) * 2 + 1] + v.y * Wf[(kb + 1) * 2 + 1]
                + v.z * Wf[(kb + 2) * 2 + 1] + v.w * Wf[(kb + 3) * 2 + 1];
        }
    }
    out[n * 2]     = o0;
    out[n * 2 + 1] = o1;
}

extern "C" void kernel_launch(void* const* d_in, const int* in_sizes, int n_in,
                              void* d_out, int out_size, void* d_ws, size_t ws_size,
                              hipStream_t stream) {
    const float* x      = (const float*)d_in[0];
    const int*   ei     = (const int*)d_in[1];
    const float* W1     = (const float*)d_in[2];
    const float* a_src1 = (const float*)d_in[3];
    const float* a_dst1 = (const float*)d_in[4];
    const float* b1     = (const float*)d_in[5];
    const float* W2     = (const float*)d_in[6];
    const float* a_src2 = (const float*)d_in[7];
    const float* a_dst2 = (const float*)d_in[8];
    const float* b2     = (const float*)d_in[9];
    const float* Wf     = (const float*)d_in[10];
    const float* bf     = (const float*)d_in[11];
    float* out = (float*)d_out;

    // workspace layout (lifetime aliasing):
    //   region A (36 MB): h1f[GN*64 u16] + l1[GN*8 u16]   (gemm1 -> layer1)
    //                     -> h2r[GN*20 u16] + out2[GN*16 f32]
    //   region B (32 MB): out1h[GN*64 u16]                (layer1 -> gemm2)
    //   region C (8 MB):  ad1[GN*8 f32] -> ad2[GN f32]
    //   ints: rowptr, deg, base_g, T, H, tmp, csr
    unsigned short* h1f = (unsigned short*)d_ws;             // GN*64 u16 (128B rows)
    unsigned short* l1  = h1f + (size_t)GN * 64;             // GN*8 u16
    unsigned short* h2r = h1f;                               // GN*20 u16 (alias)
    float* out2 = (float*)(h2r + (size_t)GN * 20);           // GN*16 f32 (alias; 4B-aligned)
    unsigned short* out1h = h1f + (size_t)GN * 72;           // GN*64 u16
    float* ad1  = (float*)(out1h + (size_t)GN * 64);         // GN*8 f32
    float* ad2  = ad1;                                       // GN (alias)
    int*   iws    = (int*)(ad1 + (size_t)GN * 8);
    int*   rowptr = iws;                                     // GN
    int*   deg    = rowptr + GN;                             // GN
    int*   base_g = deg + GN;                                // NBUK+1
    int*   T      = base_g + (NBUK + 1);                     // NBUK
    int*   H      = T + NBUK;                                // NBLK_E*NBUK
    int*   tmp    = H + (size_t)NBLK_E * NBUK;               // GE
    int*   csr    = tmp + GE;                                // GE

    // CSR build via bucket sort (no global atomics, coalesced writes)
    k_hist   <<<NBLK_E, 256, 0, stream>>>(ei, H);
    k_scanH  <<<NBUK,   256, 0, stream>>>(H, T);
    k_scanT  <<<1,      256, 0, stream>>>(T, base_g);
    k_scatter<<<NBLK_E, 256, 0, stream>>>(ei, H, base_g, tmp);
    k_build  <<<NBUK,   256, 0, stream>>>(base_g, tmp, rowptr, deg, csr);

    k_gemm1  <<<(GN + 63) / 64, 256, 0, stream>>>(x, W1, a_src1, a_dst1, h1f, l1, ad1);
    k_layer1 <<<GN / 4, 256, 0, stream>>>(rowptr, deg, csr, h1f, l1, ad1, out1h);
    k_gemm2  <<<(GN + 63) / 64, 256, 0, stream>>>(out1h, b1, W2, a_src2, a_dst2, h2r, ad2);
    k_layer2 <<<GN / 4, 256, 0, stream>>>(rowptr, deg, csr, h2r, ad2, out2);
    k_final  <<<(N_NODES + 255) / 256, 256, 0, stream>>>(out2, b2, Wf, bf, out);
}

// Round 7
// 600.520 us; speedup vs baseline: 1.2051x; 1.2051x over previous
//
#include <hip/hip_runtime.h>

// Problem constants (fixed by the reference setup)
constexpr int N_NODES = 50000;
constexpr int G = 5;
constexpr int E = 850000;            // E0 (800000) + N self-loops
constexpr int GN = G * N_NODES;      // 250000
constexpr int GE = G * E;            // 4,250,000
constexpr float SLOPE = 0.2f;

// Bucket sort parameters
constexpr int NPB = 1024;                        // nodes per bucket
constexpr int NBUK = (GN + NPB - 1) / NPB;       // 245
constexpr int EPB = 4096;                        // edges per block (256 thr x 16)
constexpr int NBLK_E = (GE + EPB - 1) / EPB;     // 1038

static __device__ __forceinline__ float lrelu(float e) {
    return e > 0.f ? e : SLOPE * e;
}
static __device__ __forceinline__ unsigned short f2h(float f) {
    union { _Float16 h; unsigned short u; } v;
    v.h = (_Float16)f;
    return v.u;
}
static __device__ __forceinline__ float h2f(unsigned short u) {
    union { unsigned short u; _Float16 h; } v;
    v.u = u;
    return (float)v.h;
}

// ---------------- pass A1: per-block bucket histogram -----------------------
__global__ __launch_bounds__(256) void k_hist(const int* __restrict__ ei,
                                              int* __restrict__ H) {
    __shared__ int hist[NBUK];
    const int t = threadIdx.x, bi = blockIdx.x;
    for (int j = t; j < NBUK; j += 256) hist[j] = 0;
    __syncthreads();
#pragma unroll
    for (int i = 0; i < 16; ++i) {
        int idx = bi * EPB + i * 256 + t;
        if (idx < GE) {
            int g = idx / E;
            int el = idx - g * E;
            int dst = ei[(size_t)g * 2 * E + E + el];
            atomicAdd(&hist[(g * N_NODES + dst) >> 10], 1);
        }
    }
    __syncthreads();
    for (int j = t; j < NBUK; j += 256) H[(size_t)bi * NBUK + j] = hist[j];
}

// ------- pass A2a: per bucket, exclusive scan of H over blocks; totals ------
__global__ __launch_bounds__(256) void k_scanH(int* __restrict__ H,
                                               int* __restrict__ T) {
    __shared__ int s[256];
    const int t = threadIdx.x, b = blockIdx.x;
    int run = 0;
    for (int c = 0; c < NBLK_E; c += 256) {
        int bi = c + t;
        int v = (bi < NBLK_E) ? H[(size_t)bi * NBUK + b] : 0;
        s[t] = v;
        for (int off = 1; off < 256; off <<= 1) {
            __syncthreads();
            int u = (t >= off) ? s[t - off] : 0;
            __syncthreads();
            s[t] += u;
        }
        __syncthreads();
        int excl = s[t] - v;
        if (bi < NBLK_E) H[(size_t)bi * NBUK + b] = run + excl;
        run += s[255];
        __syncthreads();
    }
    if (t == 0) T[b] = run;
}

// ------- pass A2b: exclusive scan of bucket totals -> bucket bases ----------
__global__ __launch_bounds__(256) void k_scanT(const int* __restrict__ T,
                                               int* __restrict__ base_g) {
    __shared__ int s[256];
    const int t = threadIdx.x;
    int v = (t < NBUK) ? T[t] : 0;
    s[t] = v;
    for (int off = 1; off < 256; off <<= 1) {
        __syncthreads();
        int u = (t >= off) ? s[t - off] : 0;
        __syncthreads();
        s[t] += u;
    }
    __syncthreads();
    if (t < NBUK) base_g[t] = s[t] - v;
    if (t == 0) base_g[NBUK] = s[255];
}

// ------- pass A3: scatter packed (dstLow10<<18 | src) into bucket groups ----
__global__ __launch_bounds__(256) void k_scatter(const int* __restrict__ ei,
                                                 const int* __restrict__ H,
                                                 const int* __restrict__ base_g,
                                                 int* __restrict__ tmp) {
    __shared__ int cnt[NBUK];
    __shared__ int off[NBUK];
    const int t = threadIdx.x, bi = blockIdx.x;
    for (int j = t; j < NBUK; j += 256) {
        cnt[j] = 0;
        off[j] = base_g[j] + H[(size_t)bi * NBUK + j];
    }
    __syncthreads();
#pragma unroll
    for (int i = 0; i < 16; ++i) {
        int idx = bi * EPB + i * 256 + t;
        if (idx < GE) {
            int g = idx / E;
            int el = idx - g * E;
            const int* eb = ei + (size_t)g * 2 * E;
            int src = eb[el];
            int dst = eb[E + el];
            int gdst = g * N_NODES + dst;
            int b = gdst >> 10;
            int rank = atomicAdd(&cnt[b], 1);
            tmp[off[b] + rank] = ((gdst & 1023) << 18) | (g * N_NODES + src);
        }
    }
}

// ------- pass B: per-bucket LDS counting sort -> rowptr/deg/csr -------------
__global__ __launch_bounds__(256) void k_build(const int* __restrict__ base_g,
                                               const int* __restrict__ tmp,
                                               int* __restrict__ rowptr,
                                               int* __restrict__ deg,
                                               int* __restrict__ csr) {
    __shared__ int degL[NPB];
    __shared__ int curL[NPB];
    __shared__ int s[256];
    const int t = threadIdx.x, b = blockIdx.x;
    const int n0 = b << 10;
    const int nn = min(NPB, GN - n0);
    const int s0 = base_g[b], s1 = base_g[b + 1];
#pragma unroll
    for (int i = 0; i < 4; ++i) degL[t * 4 + i] = 0;
    __syncthreads();
    for (int i = s0 + t; i < s1; i += 256)
        atomicAdd(&degL[tmp[i] >> 18], 1);
    __syncthreads();
    int j0 = t * 4;
    int d0 = degL[j0], d1 = degL[j0 + 1], d2 = degL[j0 + 2], d3 = degL[j0 + 3];
    int tsum = d0 + d1 + d2 + d3;
    s[t] = tsum;
    for (int off = 1; off < 256; off <<= 1) {
        __syncthreads();
        int u = (t >= off) ? s[t - off] : 0;
        __syncthreads();
        s[t] += u;
    }
    __syncthreads();
    int excl = s[t] - tsum;
    int p0 = excl, p1 = p0 + d0, p2 = p1 + d1, p3 = p2 + d2;
    curL[j0] = p0; curL[j0 + 1] = p1; curL[j0 + 2] = p2; curL[j0 + 3] = p3;
    if (j0     < nn) { rowptr[n0 + j0]     = s0 + p0; deg[n0 + j0]     = d0; }
    if (j0 + 1 < nn) { rowptr[n0 + j0 + 1] = s0 + p1; deg[n0 + j0 + 1] = d1; }
    if (j0 + 2 < nn) { rowptr[n0 + j0 + 2] = s0 + p2; deg[n0 + j0 + 2] = d2; }
    if (j0 + 3 < nn) { rowptr[n0 + j0 + 3] = s0 + p3; deg[n0 + j0 + 3] = d3; }
    __syncthreads();
    for (int i = s0 + t; i < s1; i += 256) {
        int e = tmp[i];
        int r = atomicAdd(&curL[e >> 18], 1);
        csr[s0 + r] = e & 0x3FFFF;
    }
}

// --- GEMM1 + fused logits: h1f[GN][64] fp16 (128B rows), l1[GN][8] fp16,
//     ad1[GN][8] fp32
__global__ __launch_bounds__(256) void k_gemm1(const float* __restrict__ x,
                                               const float* __restrict__ W1,
                                               const float* __restrict__ a_src,
                                               const float* __restrict__ a_dst,
                                               unsigned short* __restrict__ h1f,
                                               unsigned short* __restrict__ l1,
                                               float* __restrict__ ad1) {
    __shared__ float Bs[128][68];
    __shared__ float As[64][65];
    __shared__ float aS[64], aD[64];
    const int t = threadIdx.x;
    const int rowBase = blockIdx.x * 64;

    const float4* W14 = (const float4*)W1;
#pragma unroll
    for (int i = 0; i < 8; ++i) {
        int v = t + i * 256;
        int k = v >> 4;
        int c = (v & 15) << 2;
        float4 w = W14[v];
        Bs[k][c] = w.x; Bs[k][c + 1] = w.y; Bs[k][c + 2] = w.z; Bs[k][c + 3] = w.w;
    }
    if (t < 64) { aS[t] = a_src[t]; aD[t] = a_dst[t]; }

    const int tx = t & 15;
    const int ty = t >> 4;
    float acc[4][4] = {};
    const float4* x4 = (const float4*)x;

    for (int kc = 0; kc < 128; kc += 64) {
        __syncthreads();
#pragma unroll
        for (int i = 0; i < 4; ++i) {
            int v = t + i * 256;
            int r = v >> 4;
            int kq = v & 15;
            int row = rowBase + r;
            float4 a = make_float4(0.f, 0.f, 0.f, 0.f);
            if (row < GN) a = x4[row * 32 + (kc >> 2) + kq];
            int kk = kq << 2;
            As[kk][r] = a.x; As[kk + 1][r] = a.y; As[kk + 2][r] = a.z; As[kk + 3][r] = a.w;
        }
        __syncthreads();
#pragma unroll 8
        for (int k = 0; k < 64; ++k) {
            float a0 = As[k][ty * 4 + 0];
            float a1 = As[k][ty * 4 + 1];
            float a2 = As[k][ty * 4 + 2];
            float a3 = As[k][ty * 4 + 3];
            float4 b = *(const float4*)&Bs[kc + k][tx * 4];
            acc[0][0] += a0 * b.x; acc[0][1] += a0 * b.y; acc[0][2] += a0 * b.z; acc[0][3] += a0 * b.w;
            acc[1][0] += a1 * b.x; acc[1][1] += a1 * b.y; acc[1][2] += a1 * b.z; acc[1][3] += a1 * b.w;
            acc[2][0] += a2 * b.x; acc[2][1] += a2 * b.y; acc[2][2] += a2 * b.z; acc[2][3] += a2 * b.w;
            acc[3][0] += a3 * b.x; acc[3][1] += a3 * b.y; acc[3][2] += a3 * b.z; acc[3][3] += a3 * b.w;
        }
    }
    const int head = tx >> 1;
    const int coff = (tx & 1) * 4;
#pragma unroll
    for (int i = 0; i < 4; ++i) {
        int row = rowBase + ty * 4 + i;
        float as_p = acc[i][0] * aS[head * 8 + coff]     + acc[i][1] * aS[head * 8 + coff + 1]
                   + acc[i][2] * aS[head * 8 + coff + 2] + acc[i][3] * aS[head * 8 + coff + 3];
        float ad_p = acc[i][0] * aD[head * 8 + coff]     + acc[i][1] * aD[head * 8 + coff + 1]
                   + acc[i][2] * aD[head * 8 + coff + 2] + acc[i][3] * aD[head * 8 + coff + 3];
        as_p += __shfl_xor(as_p, 1);
        ad_p += __shfl_xor(ad_p, 1);
        if (row < GN) {
            ushort4 fv = make_ushort4(f2h(acc[i][0]), f2h(acc[i][1]), f2h(acc[i][2]), f2h(acc[i][3]));
            *(ushort4*)(h1f + (size_t)row * 64 + tx * 4) = fv;
            if ((tx & 1) == 0) {
                l1[(size_t)row * 8 + head] = f2h(as_p);
                ad1[row * 8 + head] = ad_p;
            }
        }
    }
}

// ------- layer-1 gather: one wave/dst; scalarized CSR walk, 8-wide ILP ------
__global__ __launch_bounds__(256) void k_layer1(const int* __restrict__ rowptr,
                                                const int* __restrict__ deg,
                                                const int* __restrict__ csr,
                                                const unsigned short* __restrict__ h1f,
                                                const unsigned short* __restrict__ l1,
                                                const float* __restrict__ ad1,
                                                unsigned short* __restrict__ out1h) {
    // d is wave-uniform; readfirstlane pins it (and everything derived) to SGPRs
    int d = __builtin_amdgcn_readfirstlane(blockIdx.x * 4 + (threadIdx.x >> 6));
    int tt = threadIdx.x & 63;          // h*8+c
    int h = tt >> 3;
    int start = rowptr[d];              // s_load
    int dg = deg[d];                    // s_load
    float ad = ad1[d * 8 + h];
    float den = 0.f, acc = 0.f;
    int j = 0;
    for (; j + 8 <= dg; j += 8) {       // 8 outstanding 1-line gathers
        int sv[8];
#pragma unroll
        for (int e = 0; e < 8; ++e) sv[e] = csr[start + j + e];   // s_loads
        float w[8];
#pragma unroll
        for (int e = 0; e < 8; ++e)
            w[e] = __expf(lrelu(h2f(l1[(size_t)sv[e] * 8 + h]) + ad));
        float g[8];
#pragma unroll
        for (int e = 0; e < 8; ++e) g[e] = h2f(h1f[(size_t)sv[e] * 64 + tt]);
#pragma unroll
        for (int e = 0; e < 8; ++e) { den += w[e]; acc += w[e] * g[e]; }
    }
    for (; j + 4 <= dg; j += 4) {
        int s0 = csr[start + j];
        int s1 = csr[start + j + 1];
        int s2 = csr[start + j + 2];
        int s3 = csr[start + j + 3];
        float w0 = __expf(lrelu(h2f(l1[(size_t)s0 * 8 + h]) + ad));
        float w1 = __expf(lrelu(h2f(l1[(size_t)s1 * 8 + h]) + ad));
        float w2 = __expf(lrelu(h2f(l1[(size_t)s2 * 8 + h]) + ad));
        float w3 = __expf(lrelu(h2f(l1[(size_t)s3 * 8 + h]) + ad));
        float g0 = h2f(h1f[(size_t)s0 * 64 + tt]);
        float g1 = h2f(h1f[(size_t)s1 * 64 + tt]);
        float g2 = h2f(h1f[(size_t)s2 * 64 + tt]);
        float g3 = h2f(h1f[(size_t)s3 * 64 + tt]);
        den += (w0 + w1) + (w2 + w3);
        acc += w0 * g0 + w1 * g1 + w2 * g2 + w3 * g3;
    }
    for (; j < dg; ++j) {
        int s0 = csr[start + j];
        float w0 = __expf(lrelu(h2f(l1[(size_t)s0 * 8 + h]) + ad));
        den += w0;
        acc += w0 * h2f(h1f[(size_t)s0 * 64 + tt]);
    }
    out1h[(size_t)d * 64 + tt] = f2h(acc / (den + 1e-16f));
}

// --- GEMM2 + fused logits: h2r[GN][20] fp16 (16 ch + logit in one 40B row) --
__global__ __launch_bounds__(256) void k_gemm2(const unsigned short* __restrict__ agg1,
                                               const float* __restrict__ b1,
                                               const float* __restrict__ W2,
                                               const float* __restrict__ a_src,
                                               const float* __restrict__ a_dst,
                                               unsigned short* __restrict__ h2r,
                                               float* __restrict__ ad2) {
    __shared__ float As[64][65];
    __shared__ float Bs[64][20];
    __shared__ float aS[16], aD[16];
    const int t = threadIdx.x;
    const int rowBase = blockIdx.x * 64;

    {
        int k = t >> 2, c = (t & 3) << 2;
        float4 w = ((const float4*)W2)[t];
        Bs[k][c] = w.x; Bs[k][c + 1] = w.y; Bs[k][c + 2] = w.z; Bs[k][c + 3] = w.w;
    }
    if (t < 16) { aS[t] = a_src[t]; aD[t] = a_dst[t]; }
    const ushort4* a4p = (const ushort4*)agg1;
    const float4* b14 = (const float4*)b1;
#pragma unroll
    for (int i = 0; i < 4; ++i) {
        int v = t + i * 256;
        int r = v >> 4;
        int kq = v & 15;
        int row = rowBase + r;
        float ax = 0.f, ay = 0.f, az = 0.f, aw = 0.f;
        if (row < GN) {
            ushort4 a = a4p[row * 16 + kq];
            float4 bb = b14[kq];
            ax = fmaxf(h2f(a.x) + bb.x, 0.f);
            ay = fmaxf(h2f(a.y) + bb.y, 0.f);
            az = fmaxf(h2f(a.z) + bb.z, 0.f);
            aw = fmaxf(h2f(a.w) + bb.w, 0.f);
        }
        int kk = kq << 2;
        As[kk][r] = ax; As[kk + 1][r] = ay; As[kk + 2][r] = az; As[kk + 3][r] = aw;
    }
    __syncthreads();
    const int r = t >> 2;
    const int cg = (t & 3) << 2;
    float acc0 = 0.f, acc1 = 0.f, acc2 = 0.f, acc3 = 0.f;
#pragma unroll 8
    for (int k = 0; k < 64; ++k) {
        float a = As[k][r];
        float4 b = *(const float4*)&Bs[k][cg];
        acc0 += a * b.x; acc1 += a * b.y; acc2 += a * b.z; acc3 += a * b.w;
    }
    float as_p = acc0 * aS[cg] + acc1 * aS[cg + 1] + acc2 * aS[cg + 2] + acc3 * aS[cg + 3];
    float ad_p = acc0 * aD[cg] + acc1 * aD[cg + 1] + acc2 * aD[cg + 2] + acc3 * aD[cg + 3];
    as_p += __shfl_xor(as_p, 1); as_p += __shfl_xor(as_p, 2);
    ad_p += __shfl_xor(ad_p, 1); ad_p += __shfl_xor(ad_p, 2);
    int row = rowBase + r;
    if (row < GN) {
        ushort4 fv = make_ushort4(f2h(acc0), f2h(acc1), f2h(acc2), f2h(acc3));
        *(ushort4*)(h2r + (size_t)row * 20 + cg) = fv;   // row*40B + cg*2 is 8B-aligned
        if ((t & 3) == 0) {
            h2r[(size_t)row * 20 + 16] = f2h(as_p);
            ad2[row] = ad_p;
        }
    }
}

// ------- layer-2 gather: one wave/dst, 16 ch x 4 edge-slots, reg adjacency --
__global__ __launch_bounds__(256) void k_layer2(const int* __restrict__ rowptr,
                                                const int* __restrict__ deg,
                                                const int* __restrict__ csr,
                                                const unsigned short* __restrict__ h2r,
                                                const float* __restrict__ ad2,
                                                float* __restrict__ out2) {
    int d = __builtin_amdgcn_readfirstlane(blockIdx.x * 4 + (threadIdx.x >> 6));
    int tt = threadIdx.x & 63;
    int c = tt & 15;
    int sub = tt >> 4;
    int start = rowptr[d];
    int dg = deg[d];
    float ad = ad2[d];
    int sv = csr[start + min(tt, dg - 1)];   // whole adjacency in registers
    int full = min(dg, 64);
    float den = 0.f, acc = 0.f;
    for (int base = 0; base < full; base += 4) {
        int j = base + sub;
        bool val = j < full;
        int s = __shfl(sv, j < 64 ? j : 0);
        const unsigned short* r = h2r + (size_t)s * 20;
        float w = val ? __expf(lrelu(h2f(r[16]) + ad)) : 0.f;
        float g = h2f(r[c]);
        den += w;
        acc += w * g;
    }
    // tail for deg > 64 (essentially never)
    for (int base = 64; base < dg; base += 4) {
        int j = base + sub;
        bool val = j < dg;
        int s = csr[start + (val ? j : 0)];
        const unsigned short* r = h2r + (size_t)s * 20;
        float w = val ? __expf(lrelu(h2f(r[16]) + ad)) : 0.f;
        float g = h2f(r[c]);
        den += w;
        acc += w * g;
    }
    acc += __shfl_xor(acc, 16); acc += __shfl_xor(acc, 32);
    den += __shfl_xor(den, 16); den += __shfl_xor(den, 32);
    if (sub == 0) out2[(size_t)d * 16 + c] = acc / (den + 1e-16f);
}

// -------- final: out[n,2] = concat_g(out2[g,n,:]+b2) @ Wf + bf --------------
__global__ __launch_bounds__(256) void k_final(const float* __restrict__ agg2,
                                               const float* __restrict__ b2,
                                               const float* __restrict__ Wf,
                                               const float* __restrict__ bf,
                                               float* __restrict__ out) {
    int n = blockIdx.x * 256 + threadIdx.x;
    if (n >= N_NODES) return;
    float o0 = bf[0], o1 = bf[1];
#pragma unroll
    for (int g = 0; g < G; ++g) {
        const float4* v4 = (const float4*)agg2 + (size_t)(g * N_NODES + n) * 4;
#pragma unroll
        for (int q = 0; q < 4; ++q) {
            float4 v = v4[q];
            float4 b = ((const float4*)b2)[q];
            v.x += b.x; v.y += b.y; v.z += b.z; v.w += b.w;
            int kb = g * 16 + q * 4;
            o0 += v.x * Wf[(kb + 0) * 2]     + v.y * Wf[(kb + 1) * 2]
                + v.z * Wf[(kb + 2) * 2]     + v.w * Wf[(kb + 3) * 2];
            o1 += v.x * Wf[(kb + 0) * 2 + 1] + v.y * Wf[(kb + 1) * 2 + 1]
                + v.z * Wf[(kb + 2) * 2 + 1] + v.w * Wf[(kb + 3) * 2 + 1];
        }
    }
    out[n * 2]     = o0;
    out[n * 2 + 1] = o1;
}

extern "C" void kernel_launch(void* const* d_in, const int* in_sizes, int n_in,
                              void* d_out, int out_size, void* d_ws, size_t ws_size,
                              hipStream_t stream) {
    const float* x      = (const float*)d_in[0];
    const int*   ei     = (const int*)d_in[1];
    const float* W1     = (const float*)d_in[2];
    const float* a_src1 = (const float*)d_in[3];
    const float* a_dst1 = (const float*)d_in[4];
    const float* b1     = (const float*)d_in[5];
    const float* W2     = (const float*)d_in[6];
    const float* a_src2 = (const float*)d_in[7];
    const float* a_dst2 = (const float*)d_in[8];
    const float* b2     = (const float*)d_in[9];
    const float* Wf     = (const float*)d_in[10];
    const float* bf     = (const float*)d_in[11];
    float* out = (float*)d_out;

    // workspace layout (lifetime aliasing):
    //   region A (36 MB): h1f[GN*64 u16] + l1[GN*8 u16]   (gemm1 -> layer1)
    //                     -> h2r[GN*20 u16] + out2[GN*16 f32]
    //   region B (32 MB): out1h[GN*64 u16]                (layer1 -> gemm2)
    //   region C (8 MB):  ad1[GN*8 f32] -> ad2[GN f32]
    //   ints: rowptr, deg, base_g, T, H, tmp, csr
    unsigned short* h1f = (unsigned short*)d_ws;             // GN*64 u16 (128B rows)
    unsigned short* l1  = h1f + (size_t)GN * 64;             // GN*8 u16
    unsigned short* h2r = h1f;                               // GN*20 u16 (alias)
    float* out2 = (float*)(h2r + (size_t)GN * 20);           // GN*16 f32 (alias; 16B-aligned)
    unsigned short* out1h = h1f + (size_t)GN * 72;           // GN*64 u16
    float* ad1  = (float*)(out1h + (size_t)GN * 64);         // GN*8 f32
    float* ad2  = ad1;                                       // GN (alias)
    int*   iws    = (int*)(ad1 + (size_t)GN * 8);
    int*   rowptr = iws;                                     // GN
    int*   deg    = rowptr + GN;                             // GN
    int*   base_g = deg + GN;                                // NBUK+1
    int*   T      = base_g + (NBUK + 1);                     // NBUK
    int*   H      = T + NBUK;                                // NBLK_E*NBUK
    int*   tmp    = H + (size_t)NBLK_E * NBUK;               // GE
    int*   csr    = tmp + GE;                                // GE

    // CSR build via bucket sort (no global atomics, coalesced writes)
    k_hist   <<<NBLK_E, 256, 0, stream>>>(ei, H);
    k_scanH  <<<NBUK,   256, 0, stream>>>(H, T);
    k_scanT  <<<1,      256, 0, stream>>>(T, base_g);
    k_scatter<<<NBLK_E, 256, 0, stream>>>(ei, H, base_g, tmp);
    k_build  <<<NBUK,   256, 0, stream>>>(base_g, tmp, rowptr, deg, csr);

    k_gemm1  <<<(GN + 63) / 64, 256, 0, stream>>>(x, W1, a_src1, a_dst1, h1f, l1, ad1);
    k_layer1 <<<GN / 4, 256, 0, stream>>>(rowptr, deg, csr, h1f, l1, ad1, out1h);
    k_gemm2  <<<(GN + 63) / 64, 256, 0, stream>>>(out1h, b1, W2, a_src2, a_dst2, h2r, ad2);
    k_layer2 <<<GN / 4, 256, 0, stream>>>(rowptr, deg, csr, h2r, ad2, out2);
    k_final  <<<(N_NODES + 255) / 256, 256, 0, stream>>>(out2, b2, Wf, bf, out);
}

// Round 8
// 563.065 us; speedup vs baseline: 1.2853x; 1.0665x over previous
//
#include <hip/hip_runtime.h>

// Problem constants (fixed by the reference setup)
constexpr int N_NODES = 50000;
constexpr int G = 5;
constexpr int E = 850000;            // E0 (800000) + N self-loops
constexpr int GN = G * N_NODES;      // 250000
constexpr int GE = G * E;            // 4,250,000
constexpr float SLOPE = 0.2f;

// Bucket sort parameters
constexpr int NPB = 1024;                        // nodes per bucket
constexpr int NBUK = (GN + NPB - 1) / NPB;       // 245
constexpr int EPB = 4096;                        // edges per block (256 thr x 16)
constexpr int NBLK_E = (GE + EPB - 1) / EPB;     // 1038

static __device__ __forceinline__ float lrelu(float e) {
    return e > 0.f ? e : SLOPE * e;
}
static __device__ __forceinline__ unsigned short f2h(float f) {
    union { _Float16 h; unsigned short u; } v;
    v.h = (_Float16)f;
    return v.u;
}
static __device__ __forceinline__ float h2f(unsigned short u) {
    union { unsigned short u; _Float16 h; } v;
    v.u = u;
    return (float)v.h;
}

// ---------------- pass A1: per-block bucket histogram -----------------------
__global__ __launch_bounds__(256) void k_hist(const int* __restrict__ ei,
                                              int* __restrict__ H) {
    __shared__ int hist[NBUK];
    const int t = threadIdx.x, bi = blockIdx.x;
    for (int j = t; j < NBUK; j += 256) hist[j] = 0;
    __syncthreads();
#pragma unroll
    for (int i = 0; i < 16; ++i) {
        int idx = bi * EPB + i * 256 + t;
        if (idx < GE) {
            int g = idx / E;
            int el = idx - g * E;
            int dst = ei[(size_t)g * 2 * E + E + el];
            atomicAdd(&hist[(g * N_NODES + dst) >> 10], 1);
        }
    }
    __syncthreads();
    for (int j = t; j < NBUK; j += 256) H[(size_t)bi * NBUK + j] = hist[j];
}

// ------- pass A2a: per bucket, exclusive scan of H over blocks; totals ------
__global__ __launch_bounds__(256) void k_scanH(int* __restrict__ H,
                                               int* __restrict__ T) {
    __shared__ int s[256];
    const int t = threadIdx.x, b = blockIdx.x;
    int run = 0;
    for (int c = 0; c < NBLK_E; c += 256) {
        int bi = c + t;
        int v = (bi < NBLK_E) ? H[(size_t)bi * NBUK + b] : 0;
        s[t] = v;
        for (int off = 1; off < 256; off <<= 1) {
            __syncthreads();
            int u = (t >= off) ? s[t - off] : 0;
            __syncthreads();
            s[t] += u;
        }
        __syncthreads();
        int excl = s[t] - v;
        if (bi < NBLK_E) H[(size_t)bi * NBUK + b] = run + excl;
        run += s[255];
        __syncthreads();
    }
    if (t == 0) T[b] = run;
}

// ------- pass A2b: exclusive scan of bucket totals -> bucket bases ----------
__global__ __launch_bounds__(256) void k_scanT(const int* __restrict__ T,
                                               int* __restrict__ base_g) {
    __shared__ int s[256];
    const int t = threadIdx.x;
    int v = (t < NBUK) ? T[t] : 0;
    s[t] = v;
    for (int off = 1; off < 256; off <<= 1) {
        __syncthreads();
        int u = (t >= off) ? s[t - off] : 0;
        __syncthreads();
        s[t] += u;
    }
    __syncthreads();
    if (t < NBUK) base_g[t] = s[t] - v;
    if (t == 0) base_g[NBUK] = s[255];
}

// ------- pass A3: scatter packed (dstLow10<<18 | src) into bucket groups ----
__global__ __launch_bounds__(256) void k_scatter(const int* __restrict__ ei,
                                                 const int* __restrict__ H,
                                                 const int* __restrict__ base_g,
                                                 int* __restrict__ tmp) {
    __shared__ int cnt[NBUK];
    __shared__ int off[NBUK];
    const int t = threadIdx.x, bi = blockIdx.x;
    for (int j = t; j < NBUK; j += 256) {
        cnt[j] = 0;
        off[j] = base_g[j] + H[(size_t)bi * NBUK + j];
    }
    __syncthreads();
#pragma unroll
    for (int i = 0; i < 16; ++i) {
        int idx = bi * EPB + i * 256 + t;
        if (idx < GE) {
            int g = idx / E;
            int el = idx - g * E;
            const int* eb = ei + (size_t)g * 2 * E;
            int src = eb[el];
            int dst = eb[E + el];
            int gdst = g * N_NODES + dst;
            int b = gdst >> 10;
            int rank = atomicAdd(&cnt[b], 1);
            tmp[off[b] + rank] = ((gdst & 1023) << 18) | (g * N_NODES + src);
        }
    }
}

// ------- pass B: per-bucket LDS counting sort -> rowptr/deg/csr -------------
__global__ __launch_bounds__(256) void k_build(const int* __restrict__ base_g,
                                               const int* __restrict__ tmp,
                                               int* __restrict__ rowptr,
                                               int* __restrict__ deg,
                                               int* __restrict__ csr) {
    __shared__ int degL[NPB];
    __shared__ int curL[NPB];
    __shared__ int s[256];
    const int t = threadIdx.x, b = blockIdx.x;
    const int n0 = b << 10;
    const int nn = min(NPB, GN - n0);
    const int s0 = base_g[b], s1 = base_g[b + 1];
#pragma unroll
    for (int i = 0; i < 4; ++i) degL[t * 4 + i] = 0;
    __syncthreads();
    for (int i = s0 + t; i < s1; i += 256)
        atomicAdd(&degL[tmp[i] >> 18], 1);
    __syncthreads();
    int j0 = t * 4;
    int d0 = degL[j0], d1 = degL[j0 + 1], d2 = degL[j0 + 2], d3 = degL[j0 + 3];
    int tsum = d0 + d1 + d2 + d3;
    s[t] = tsum;
    for (int off = 1; off < 256; off <<= 1) {
        __syncthreads();
        int u = (t >= off) ? s[t - off] : 0;
        __syncthreads();
        s[t] += u;
    }
    __syncthreads();
    int excl = s[t] - tsum;
    int p0 = excl, p1 = p0 + d0, p2 = p1 + d1, p3 = p2 + d2;
    curL[j0] = p0; curL[j0 + 1] = p1; curL[j0 + 2] = p2; curL[j0 + 3] = p3;
    if (j0     < nn) { rowptr[n0 + j0]     = s0 + p0; deg[n0 + j0]     = d0; }
    if (j0 + 1 < nn) { rowptr[n0 + j0 + 1] = s0 + p1; deg[n0 + j0 + 1] = d1; }
    if (j0 + 2 < nn) { rowptr[n0 + j0 + 2] = s0 + p2; deg[n0 + j0 + 2] = d2; }
    if (j0 + 3 < nn) { rowptr[n0 + j0 + 3] = s0 + p3; deg[n0 + j0 + 3] = d3; }
    __syncthreads();
    for (int i = s0 + t; i < s1; i += 256) {
        int e = tmp[i];
        int r = atomicAdd(&curL[e >> 18], 1);
        csr[s0 + r] = e & 0x3FFFF;
    }
}

// --- GEMM1 + fused logits: h1f[GN][64] fp16 (128B rows), l1[GN][8] fp16,
//     ad1[GN][8] fp32
__global__ __launch_bounds__(256) void k_gemm1(const float* __restrict__ x,
                                               const float* __restrict__ W1,
                                               const float* __restrict__ a_src,
                                               const float* __restrict__ a_dst,
                                               unsigned short* __restrict__ h1f,
                                               unsigned short* __restrict__ l1,
                                               float* __restrict__ ad1) {
    __shared__ float Bs[128][68];
    __shared__ float As[64][65];
    __shared__ float aS[64], aD[64];
    const int t = threadIdx.x;
    const int rowBase = blockIdx.x * 64;

    const float4* W14 = (const float4*)W1;
#pragma unroll
    for (int i = 0; i < 8; ++i) {
        int v = t + i * 256;
        int k = v >> 4;
        int c = (v & 15) << 2;
        float4 w = W14[v];
        Bs[k][c] = w.x; Bs[k][c + 1] = w.y; Bs[k][c + 2] = w.z; Bs[k][c + 3] = w.w;
    }
    if (t < 64) { aS[t] = a_src[t]; aD[t] = a_dst[t]; }

    const int tx = t & 15;
    const int ty = t >> 4;
    float acc[4][4] = {};
    const float4* x4 = (const float4*)x;

    for (int kc = 0; kc < 128; kc += 64) {
        __syncthreads();
#pragma unroll
        for (int i = 0; i < 4; ++i) {
            int v = t + i * 256;
            int r = v >> 4;
            int kq = v & 15;
            int row = rowBase + r;
            float4 a = make_float4(0.f, 0.f, 0.f, 0.f);
            if (row < GN) a = x4[row * 32 + (kc >> 2) + kq];
            int kk = kq << 2;
            As[kk][r] = a.x; As[kk + 1][r] = a.y; As[kk + 2][r] = a.z; As[kk + 3][r] = a.w;
        }
        __syncthreads();
#pragma unroll 8
        for (int k = 0; k < 64; ++k) {
            float a0 = As[k][ty * 4 + 0];
            float a1 = As[k][ty * 4 + 1];
            float a2 = As[k][ty * 4 + 2];
            float a3 = As[k][ty * 4 + 3];
            float4 b = *(const float4*)&Bs[kc + k][tx * 4];
            acc[0][0] += a0 * b.x; acc[0][1] += a0 * b.y; acc[0][2] += a0 * b.z; acc[0][3] += a0 * b.w;
            acc[1][0] += a1 * b.x; acc[1][1] += a1 * b.y; acc[1][2] += a1 * b.z; acc[1][3] += a1 * b.w;
            acc[2][0] += a2 * b.x; acc[2][1] += a2 * b.y; acc[2][2] += a2 * b.z; acc[2][3] += a2 * b.w;
            acc[3][0] += a3 * b.x; acc[3][1] += a3 * b.y; acc[3][2] += a3 * b.z; acc[3][3] += a3 * b.w;
        }
    }
    const int head = tx >> 1;
    const int coff = (tx & 1) * 4;
#pragma unroll
    for (int i = 0; i < 4; ++i) {
        int row = rowBase + ty * 4 + i;
        float as_p = acc[i][0] * aS[head * 8 + coff]     + acc[i][1] * aS[head * 8 + coff + 1]
                   + acc[i][2] * aS[head * 8 + coff + 2] + acc[i][3] * aS[head * 8 + coff + 3];
        float ad_p = acc[i][0] * aD[head * 8 + coff]     + acc[i][1] * aD[head * 8 + coff + 1]
                   + acc[i][2] * aD[head * 8 + coff + 2] + acc[i][3] * aD[head * 8 + coff + 3];
        as_p += __shfl_xor(as_p, 1);
        ad_p += __shfl_xor(ad_p, 1);
        if (row < GN) {
            ushort4 fv = make_ushort4(f2h(acc[i][0]), f2h(acc[i][1]), f2h(acc[i][2]), f2h(acc[i][3]));
            *(ushort4*)(h1f + (size_t)row * 64 + tx * 4) = fv;
            if ((tx & 1) == 0) {
                l1[(size_t)row * 8 + head] = f2h(as_p);
                ad1[row * 8 + head] = ad_p;
            }
        }
    }
}

// ------- layer-1 gather: one wave = one dst, 2 edges in flight --------------
// lanes 0-31: even edges, lanes 32-63: odd edges; each lane = 2 fp16 channels.
__global__ __launch_bounds__(256) void k_layer1(const int* __restrict__ rowptr,
                                                const int* __restrict__ deg,
                                                const int* __restrict__ csr,
                                                const unsigned short* __restrict__ h1f,
                                                const unsigned short* __restrict__ l1,
                                                const float* __restrict__ ad1,
                                                unsigned short* __restrict__ out1h) {
    int d = __builtin_amdgcn_readfirstlane(blockIdx.x * 4 + (threadIdx.x >> 6));
    int tt = threadIdx.x & 63;
    int half = tt >> 5;               // edge parity
    int p = tt & 31;                  // channel pair (ch 2p, 2p+1)
    int h = p >> 2;                   // head
    int start = rowptr[d];            // SGPR
    int dg = deg[d];                  // SGPR
    float ad = ad1[d * 8 + h];
    const unsigned int* h1d = (const unsigned int*)h1f;   // row = 32 dwords
    float den = 0.f, accx = 0.f, accy = 0.f;
    int j = 0;
    for (; j + 8 <= dg; j += 8) {     // 4 pairs = 8 edges per iteration
        int s[4];
#pragma unroll
        for (int e = 0; e < 4; ++e) {
            int se = csr[start + j + 2 * e];       // s_load
            int so = csr[start + j + 2 * e + 1];   // s_load
            s[e] = half ? so : se;                 // v_cndmask
        }
        float w[4];
#pragma unroll
        for (int e = 0; e < 4; ++e)
            w[e] = __expf(lrelu(h2f(l1[(size_t)s[e] * 8 + h]) + ad));
        unsigned int gp[4];
#pragma unroll
        for (int e = 0; e < 4; ++e) gp[e] = h1d[(size_t)s[e] * 32 + p];
#pragma unroll
        for (int e = 0; e < 4; ++e) {
            den += w[e];
            accx += w[e] * h2f((unsigned short)(gp[e] & 0xffff));
            accy += w[e] * h2f((unsigned short)(gp[e] >> 16));
        }
    }
    for (; j < dg; j += 2) {          // predicated tail pairs
        int se = csr[start + j];
        int so = (j + 1 < dg) ? csr[start + j + 1] : se;
        int s = half ? so : se;
        float w = __expf(lrelu(h2f(l1[(size_t)s * 8 + h]) + ad));
        if (j + half >= dg) w = 0.f;
        unsigned int gp = h1d[(size_t)s * 32 + p];
        den += w;
        accx += w * h2f((unsigned short)(gp & 0xffff));
        accy += w * h2f((unsigned short)(gp >> 16));
    }
    accx += __shfl_xor(accx, 32);
    accy += __shfl_xor(accy, 32);
    den  += __shfl_xor(den, 32);
    if (half == 0) {
        float inv = 1.f / (den + 1e-16f);
        unsigned int pk = (unsigned int)f2h(accx * inv)
                        | ((unsigned int)f2h(accy * inv) << 16);
        ((unsigned int*)out1h)[(size_t)d * 32 + p] = pk;
    }
}

// --- GEMM2 + fused logits: h2r[GN][20] fp16 (16 ch + logit in one 40B row) --
__global__ __launch_bounds__(256) void k_gemm2(const unsigned short* __restrict__ agg1,
                                               const float* __restrict__ b1,
                                               const float* __restrict__ W2,
                                               const float* __restrict__ a_src,
                                               const float* __restrict__ a_dst,
                                               unsigned short* __restrict__ h2r,
                                               float* __restrict__ ad2) {
    __shared__ float As[64][65];
    __shared__ float Bs[64][20];
    __shared__ float aS[16], aD[16];
    const int t = threadIdx.x;
    const int rowBase = blockIdx.x * 64;

    {
        int k = t >> 2, c = (t & 3) << 2;
        float4 w = ((const float4*)W2)[t];
        Bs[k][c] = w.x; Bs[k][c + 1] = w.y; Bs[k][c + 2] = w.z; Bs[k][c + 3] = w.w;
    }
    if (t < 16) { aS[t] = a_src[t]; aD[t] = a_dst[t]; }
    const ushort4* a4p = (const ushort4*)agg1;
    const float4* b14 = (const float4*)b1;
#pragma unroll
    for (int i = 0; i < 4; ++i) {
        int v = t + i * 256;
        int r = v >> 4;
        int kq = v & 15;
        int row = rowBase + r;
        float ax = 0.f, ay = 0.f, az = 0.f, aw = 0.f;
        if (row < GN) {
            ushort4 a = a4p[row * 16 + kq];
            float4 bb = b14[kq];
            ax = fmaxf(h2f(a.x) + bb.x, 0.f);
            ay = fmaxf(h2f(a.y) + bb.y, 0.f);
            az = fmaxf(h2f(a.z) + bb.z, 0.f);
            aw = fmaxf(h2f(a.w) + bb.w, 0.f);
        }
        int kk = kq << 2;
        As[kk][r] = ax; As[kk + 1][r] = ay; As[kk + 2][r] = az; As[kk + 3][r] = aw;
    }
    __syncthreads();
    const int r = t >> 2;
    const int cg = (t & 3) << 2;
    float acc0 = 0.f, acc1 = 0.f, acc2 = 0.f, acc3 = 0.f;
#pragma unroll 8
    for (int k = 0; k < 64; ++k) {
        float a = As[k][r];
        float4 b = *(const float4*)&Bs[k][cg];
        acc0 += a * b.x; acc1 += a * b.y; acc2 += a * b.z; acc3 += a * b.w;
    }
    float as_p = acc0 * aS[cg] + acc1 * aS[cg + 1] + acc2 * aS[cg + 2] + acc3 * aS[cg + 3];
    float ad_p = acc0 * aD[cg] + acc1 * aD[cg + 1] + acc2 * aD[cg + 2] + acc3 * aD[cg + 3];
    as_p += __shfl_xor(as_p, 1); as_p += __shfl_xor(as_p, 2);
    ad_p += __shfl_xor(ad_p, 1); ad_p += __shfl_xor(ad_p, 2);
    int row = rowBase + r;
    if (row < GN) {
        ushort4 fv = make_ushort4(f2h(acc0), f2h(acc1), f2h(acc2), f2h(acc3));
        *(ushort4*)(h2r + (size_t)row * 20 + cg) = fv;   // row*40B + cg*2 is 8B-aligned
        if ((t & 3) == 0) {
            h2r[(size_t)row * 20 + 16] = f2h(as_p);
            ad2[row] = ad_p;
        }
    }
}

// ------- layer-2 gather: one wave/dst, 8 edge-slots x 8 ch-pairs ------------
__global__ __launch_bounds__(256) void k_layer2(const int* __restrict__ rowptr,
                                                const int* __restrict__ deg,
                                                const int* __restrict__ csr,
                                                const unsigned short* __restrict__ h2r,
                                                const float* __restrict__ ad2,
                                                float* __restrict__ out2) {
    int d = __builtin_amdgcn_readfirstlane(blockIdx.x * 4 + (threadIdx.x >> 6));
    int tt = threadIdx.x & 63;
    int p = tt & 7;                   // channel pair (ch 2p, 2p+1)
    int sub = tt >> 3;                // 8 edge slots
    int start = rowptr[d];
    int dg = deg[d];
    float ad = ad2[d];
    int sv = csr[start + min(tt, dg - 1)];   // whole adjacency in registers
    int full = min(dg, 64);
    float den = 0.f, accx = 0.f, accy = 0.f;
    for (int base = 0; base < full; base += 8) {
        int j = base + sub;
        bool val = j < full;
        int s = __shfl(sv, j < 64 ? j : 0);
        const unsigned short* r = h2r + (size_t)s * 20;
        float w = val ? __expf(lrelu(h2f(r[16]) + ad)) : 0.f;
        unsigned int gp = *(const unsigned int*)(r + p * 2);
        den += w;
        accx += w * h2f((unsigned short)(gp & 0xffff));
        accy += w * h2f((unsigned short)(gp >> 16));
    }
    // tail for deg > 64 (essentially never)
    for (int base = 64; base < dg; base += 8) {
        int j = base + sub;
        bool val = j < dg;
        int s = csr[start + (val ? j : 0)];
        const unsigned short* r = h2r + (size_t)s * 20;
        float w = val ? __expf(lrelu(h2f(r[16]) + ad)) : 0.f;
        unsigned int gp = *(const unsigned int*)(r + p * 2);
        den += w;
        accx += w * h2f((unsigned short)(gp & 0xffff));
        accy += w * h2f((unsigned short)(gp >> 16));
    }
    accx += __shfl_xor(accx, 8); accx += __shfl_xor(accx, 16); accx += __shfl_xor(accx, 32);
    accy += __shfl_xor(accy, 8); accy += __shfl_xor(accy, 16); accy += __shfl_xor(accy, 32);
    den  += __shfl_xor(den, 8);  den  += __shfl_xor(den, 16);  den  += __shfl_xor(den, 32);
    if (sub == 0) {
        float inv = 1.f / (den + 1e-16f);
        ((float2*)out2)[(size_t)d * 8 + p] = make_float2(accx * inv, accy * inv);
    }
}

// -------- final: out[n,2] = concat_g(out2[g,n,:]+b2) @ Wf + bf --------------
__global__ __launch_bounds__(256) void k_final(const float* __restrict__ agg2,
                                               const float* __restrict__ b2,
                                               const float* __restrict__ Wf,
                                               const float* __restrict__ bf,
                                               float* __restrict__ out) {
    int n = blockIdx.x * 256 + threadIdx.x;
    if (n >= N_NODES) return;
    float o0 = bf[0], o1 = bf[1];
#pragma unroll
    for (int g = 0; g < G; ++g) {
        const float4* v4 = (const float4*)agg2 + (size_t)(g * N_NODES + n) * 4;
#pragma unroll
        for (int q = 0; q < 4; ++q) {
            float4 v = v4[q];
            float4 b = ((const float4*)b2)[q];
            v.x += b.x; v.y += b.y; v.z += b.z; v.w += b.w;
            int kb = g * 16 + q * 4;
            o0 += v.x * Wf[(kb + 0) * 2]     + v.y * Wf[(kb + 1) * 2]
                + v.z * Wf[(kb + 2) * 2]     + v.w * Wf[(kb + 3) * 2];
            o1 += v.x * Wf[(kb + 0) * 2 + 1] + v.y * Wf[(kb + 1) * 2 + 1]
                + v.z * Wf[(kb + 2) * 2 + 1] + v.w * Wf[(kb + 3) * 2 + 1];
        }
    }
    out[n * 2]     = o0;
    out[n * 2 + 1] = o1;
}

extern "C" void kernel_launch(void* const* d_in, const int* in_sizes, int n_in,
                              void* d_out, int out_size, void* d_ws, size_t ws_size,
                              hipStream_t stream) {
    const float* x      = (const float*)d_in[0];
    const int*   ei     = (const int*)d_in[1];
    const float* W1     = (const float*)d_in[2];
    const float* a_src1 = (const float*)d_in[3];
    const float* a_dst1 = (const float*)d_in[4];
    const float* b1     = (const float*)d_in[5];
    const float* W2     = (const float*)d_in[6];
    const float* a_src2 = (const float*)d_in[7];
    const float* a_dst2 = (const float*)d_in[8];
    const float* b2     = (const float*)d_in[9];
    const float* Wf     = (const float*)d_in[10];
    const float* bf     = (const float*)d_in[11];
    float* out = (float*)d_out;

    // workspace layout (lifetime aliasing):
    //   region A (36 MB): h1f[GN*64 u16] + l1[GN*8 u16]   (gemm1 -> layer1)
    //                     -> h2r[GN*20 u16] + out2[GN*16 f32]
    //   region B (32 MB): out1h[GN*64 u16]                (layer1 -> gemm2)
    //   region C (8 MB):  ad1[GN*8 f32] -> ad2[GN f32]
    //   ints: rowptr, deg, base_g, T, H, tmp, csr
    unsigned short* h1f = (unsigned short*)d_ws;             // GN*64 u16 (128B rows)
    unsigned short* l1  = h1f + (size_t)GN * 64;             // GN*8 u16
    unsigned short* h2r = h1f;                               // GN*20 u16 (alias)
    float* out2 = (float*)(h2r + (size_t)GN * 20);           // GN*16 f32 (alias; 8B-aligned)
    unsigned short* out1h = h1f + (size_t)GN * 72;           // GN*64 u16
    float* ad1  = (float*)(out1h + (size_t)GN * 64);         // GN*8 f32
    float* ad2  = ad1;                                       // GN (alias)
    int*   iws    = (int*)(ad1 + (size_t)GN * 8);
    int*   rowptr = iws;                                     // GN
    int*   deg    = rowptr + GN;                             // GN
    int*   base_g = deg + GN;                                // NBUK+1
    int*   T      = base_g + (NBUK + 1);                     // NBUK
    int*   H      = T + NBUK;                                // NBLK_E*NBUK
    int*   tmp    = H + (size_t)NBLK_E * NBUK;               // GE
    int*   csr    = tmp + GE;                                // GE

    // CSR build via bucket sort (no global atomics, coalesced writes)
    k_hist   <<<NBLK_E, 256, 0, stream>>>(ei, H);
    k_scanH  <<<NBUK,   256, 0, stream>>>(H, T);
    k_scanT  <<<1,      256, 0, stream>>>(T, base_g);
    k_scatter<<<NBLK_E, 256, 0, stream>>>(ei, H, base_g, tmp);
    k_build  <<<NBUK,   256, 0, stream>>>(base_g, tmp, rowptr, deg, csr);

    k_gemm1  <<<(GN + 63) / 64, 256, 0, stream>>>(x, W1, a_src1, a_dst1, h1f, l1, ad1);
    k_layer1 <<<GN / 4, 256, 0, stream>>>(rowptr, deg, csr, h1f, l1, ad1, out1h);
    k_gemm2  <<<(GN + 63) / 64, 256, 0, stream>>>(out1h, b1, W2, a_src2, a_dst2, h2r, ad2);
    k_layer2 <<<GN / 4, 256, 0, stream>>>(rowptr, deg, csr, h2r, ad2, out2);
    k_final  <<<(N_NODES + 255) / 256, 256, 0, stream>>>(out2, b2, Wf, bf, out);
}